// Round 6
// baseline (464.500 us; speedup 1.0000x reference)
//
#include <hip/hip_runtime.h>
#include <stdint.h>
#include <math.h>

using f32x4  = __attribute__((ext_vector_type(4)))  float;
using f32x16 = __attribute__((ext_vector_type(16))) float;
using s16x8  = __attribute__((ext_vector_type(8)))  short;

#define DI __device__ __forceinline__

DI unsigned short f2bf(float f) {
  unsigned u = __float_as_uint(f);
  u += 0x7FFFu + ((u >> 16) & 1u);
  return (unsigned short)(u >> 16);
}
DI float bf2f(unsigned short h) { return __uint_as_float((unsigned)h << 16); }

// ---------------------------------------------------------------- f32 -> bf16
__global__ void k_cvt_bf16(const float* __restrict__ in, unsigned short* __restrict__ out, int n4) {
  int i = blockIdx.x * blockDim.x + threadIdx.x;
  const int stride = gridDim.x * blockDim.x;
  for (; i < n4; i += stride) {
    float4 v = reinterpret_cast<const float4*>(in)[i];
    ushort4 o;
    o.x = f2bf(v.x); o.y = f2bf(v.y); o.z = f2bf(v.z); o.w = f2bf(v.w);
    reinterpret_cast<ushort4*>(out)[i] = o;
  }
}

// ---------------------------------------------------------------- rope tables (2048 x 32)
__global__ void k_rope_table(float* __restrict__ cost, float* __restrict__ sint) {
  const int idx = blockIdx.x * 256 + threadIdx.x;  // 65536
  const int s = idx >> 5, fi = idx & 31;
  const double invf = pow(10000.0, -(double)fi / 32.0);
  const float ang = (float)s * (float)invf;
  cost[idx] = (float)cos((double)ang);
  sint[idx] = (float)sin((double)ang);
}

// ---------------------------------------------------------------- bf16 GEMM  C[M][N] = A[M][K]*B[N][K]^T + bias
__global__ __launch_bounds__(256) void k_gemm_bt(
    const unsigned short* __restrict__ A, const unsigned short* __restrict__ B,
    const float* __restrict__ bias, float* __restrict__ C, int M, int N, int K) {
  __shared__ unsigned short As[128 * 32], Bs[128 * 32];
  const int tid = threadIdx.x, l = tid & 63, w = tid >> 6;
  const int wr = w >> 1, wc = w & 1;
  const int m0 = blockIdx.x * 128, n0 = blockIdx.y * 128;
  const int srow = tid >> 2, scol = (tid & 3) * 8;
  f32x4 acc[4][4] = {};
  for (int k0 = 0; k0 < K; k0 += 32) {
    s16x8 a0 = *(const s16x8*)(A + (size_t)(m0 + srow) * K + k0 + scol);
    s16x8 a1 = *(const s16x8*)(A + (size_t)(m0 + 64 + srow) * K + k0 + scol);
    s16x8 b0 = *(const s16x8*)(B + (size_t)(n0 + srow) * K + k0 + scol);
    s16x8 b1 = *(const s16x8*)(B + (size_t)(n0 + 64 + srow) * K + k0 + scol);
    __syncthreads();
    *(s16x8*)&As[srow * 32 + scol] = a0;
    *(s16x8*)&As[(64 + srow) * 32 + scol] = a1;
    *(s16x8*)&Bs[srow * 32 + scol] = b0;
    *(s16x8*)&Bs[(64 + srow) * 32 + scol] = b1;
    __syncthreads();
    s16x8 af[4], bf[4];
#pragma unroll
    for (int i = 0; i < 4; i++)
      af[i] = *(const s16x8*)&As[(wr * 64 + i * 16 + (l & 15)) * 32 + (l >> 4) * 8];
#pragma unroll
    for (int j = 0; j < 4; j++)
      bf[j] = *(const s16x8*)&Bs[(wc * 64 + j * 16 + (l & 15)) * 32 + (l >> 4) * 8];
#pragma unroll
    for (int i = 0; i < 4; i++)
#pragma unroll
      for (int j = 0; j < 4; j++)
        acc[i][j] = __builtin_amdgcn_mfma_f32_16x16x32_bf16(af[i], bf[j], acc[i][j], 0, 0, 0);
  }
#pragma unroll
  for (int i = 0; i < 4; i++) {
    const int row = m0 + wr * 64 + i * 16 + (l >> 4) * 4;
#pragma unroll
    for (int j = 0; j < 4; j++) {
      const int col = n0 + wc * 64 + j * 16 + (l & 15);
      const float bv = bias ? bias[col] : 0.f;
#pragma unroll
      for (int r = 0; r < 4; r++) C[(size_t)(row + r) * N + col] = acc[i][j][r] + bv;
    }
  }
}

// ---------------------------------------------------------------- RoPE + relayout
// rotate_half pairs heads h^8 (sign - for h<8); tables indexed by (s, d&31).
__global__ void k_rope_relayout(const float* __restrict__ qkv, const float* __restrict__ cost,
                                const float* __restrict__ sint,
                                unsigned short* __restrict__ qh, unsigned short* __restrict__ kh,
                                unsigned short* __restrict__ vt) {
  const int s = blockIdx.x, t = threadIdx.x;
  const float* row = qkv + (size_t)s * 3072;
  const int c = t * 4;
  const int d = c >> 4;
  const int hbase = c & 15;
  const float cv = cost[s * 32 + (d & 31)];
  const float sv = sint[s * 32 + (d & 31)];
  const float sgn = (hbase < 8) ? -1.f : 1.f;
  {
    float4 v = *(const float4*)(row + c);
    float4 v2 = *(const float4*)(row + (c ^ 8));
    const float* vp = (const float*)&v;
    const float* vp2 = (const float*)&v2;
#pragma unroll
    for (int i = 0; i < 4; i++) {
      float val = vp[i] * cv + sgn * vp2[i] * sv;
      qh[(size_t)(hbase + i) * (2048 * 64) + s * 64 + d] = f2bf(val);
    }
  }
  {
    float4 v = *(const float4*)(row + 1024 + c);
    float4 v2 = *(const float4*)(row + 1024 + (c ^ 8));
    const float* vp = (const float*)&v;
    const float* vp2 = (const float*)&v2;
#pragma unroll
    for (int i = 0; i < 4; i++) {
      float val = vp[i] * cv + sgn * vp2[i] * sv;
      kh[(size_t)(hbase + i) * (2048 * 64) + s * 64 + d] = f2bf(val);
    }
  }
  {
    float4 v = *(const float4*)(row + 2048 + c);
    const float* vp = (const float*)&v;
#pragma unroll
    for (int i = 0; i < 4; i++)
      vt[(size_t)(hbase + i) * (64 * 2048) + (size_t)d * 2048 + s] = f2bf(vp[i]);
  }
}

// ---------------------------------------------------------------- bias+mask pre-pass
// Coalesced float4/int4 loads (1 KB per wave-instr), in-register 4x4 k<->h
// transpose via shfl_xor(4)/shfl_xor(8), 8 B/lane stores merged in L2 across
// the unrolled j-loop. No LDS, no barriers, deep ILP (j+1 loads prefetched).
// in : bias fp32 [j][k][h16], mask int32 same
// out: bmG bf16 [h][ko=k/4][j][ki=k%4]
// wave-iter: 1 j x 64 k x 16 h. lane l: b=l&3 (h-quad), s=(l>>2)&3, t=l>>4.
// load i: float4 at (j, k0 + (l>>2) + 16i, 4b) -> contiguous 1 KB across wave.
// after transpose lane holds h=4b+s, k = k0+16i+4t+{0..3} -> one 8 B word.
__global__ __launch_bounds__(256, 4) void k_prep(const float* __restrict__ bias,
                                                 const int* __restrict__ mask,
                                                 unsigned short* __restrict__ bmG) {
  const int tid = threadIdx.x, w = tid >> 6, l = tid & 63;
  const int b = l & 3, s = (l >> 2) & 3, tq = l >> 4;
  const int kk = l >> 2;
  const int jt = blockIdx.x, kt = blockIdx.y;  // grid (128, 8)
  const int k0 = (kt * 4 + w) * 64;
  const int hh = 4 * b + s;
  const int s0 = s & 1, s1 = (s >> 1) & 1;
  const int jbase = jt * 16;

#define PREP_LOAD(BV, MV, JJ)                                                        \
  {                                                                                  \
    const size_t rb = ((size_t)(jbase + (JJ)) * 2048 + k0 + kk) * 16 + 4 * b;        \
    _Pragma("unroll") for (int i = 0; i < 4; ++i)                                    \
        BV[i] = *(const float4*)(bias + rb + (size_t)i * 256);                       \
    _Pragma("unroll") for (int i = 0; i < 4; ++i)                                    \
        MV[i] = *(const int4*)(mask + rb + (size_t)i * 256);                         \
  }

  float4 bA[4]; int4 mA[4];
  PREP_LOAD(bA, mA, 0)

#pragma unroll
  for (int jj = 0; jj < 16; ++jj) {
    float4 bB[4]; int4 mB[4];
    if (jj < 15) PREP_LOAD(bB, mB, jj + 1)
    const int j = jbase + jj;
#pragma unroll
    for (int i = 0; i < 4; ++i) {
      const float* bp = (const float*)&bA[i];
      const int* mp = (const int*)&mA[i];
      float f[4];
#pragma unroll
      for (int c = 0; c < 4; ++c) f[c] = mp[c] ? bp[c] : -1.0e8f;
      float pf[4];
#pragma unroll
      for (int c = 0; c < 4; ++c) pf[c] = __shfl_xor(f[c], 4);
      float g[4];
      g[0] = (s0 == 0) ? f[0] : pf[1];
      g[1] = (s0 == 1) ? f[1] : pf[0];
      g[2] = (s0 == 0) ? f[2] : pf[3];
      g[3] = (s0 == 1) ? f[3] : pf[2];
      float pg[4];
#pragma unroll
      for (int c = 0; c < 4; ++c) pg[c] = __shfl_xor(g[c], 8);
      float d[4];
      d[0] = (s1 == 0) ? g[0] : pg[2];
      d[1] = (s1 == 0) ? g[1] : pg[3];
      d[2] = (s1 == 1) ? g[2] : pg[0];
      d[3] = (s1 == 1) ? g[3] : pg[1];
      const int ko = (k0 >> 2) + 4 * i + tq;
      uint2 o;
      o.x = (unsigned)f2bf(d[0]) | ((unsigned)f2bf(d[1]) << 16);
      o.y = (unsigned)f2bf(d[2]) | ((unsigned)f2bf(d[3]) << 16);
      *(uint2*)(bmG + (((size_t)hh * 512 + ko) * 2048 + j) * 4) = o;
    }
#pragma unroll
    for (int i = 0; i < 4; ++i) { bA[i] = bB[i]; mA[i] = mB[i]; }
  }
#undef PREP_LOAD
}

// ---------------------------------------------------------------- attention (barrier-free)
// grid (q4=4, jt=64, ks=4), 256 threads = 4 waves, 1 head/wave, 32 q-rows, 512 k per block
__global__ __launch_bounds__(256, 4) void k_attn(
    const unsigned short* __restrict__ bmG,
    const unsigned short* __restrict__ qh, const unsigned short* __restrict__ kh,
    const unsigned short* __restrict__ vt,
    float* __restrict__ Opart, float* __restrict__ ML) {
  const int tid = threadIdx.x, l = tid & 63, w = tid >> 6;
  const int hi = l >> 5, ln = l & 31;
  const int q4 = blockIdx.x, jt = blockIdx.y, ks = blockIdx.z;
  const int j0 = jt * 32, h = q4 * 4 + w, kstart = ks * 512;

  s16x8 qf[4];
  {
    const unsigned short* qb = qh + ((size_t)h * 2048 + (j0 + ln)) * 64 + 8 * hi;
#pragma unroll
    for (int ds = 0; ds < 4; ds++) qf[ds] = *(const s16x8*)(qb + ds * 16);
  }
  const unsigned short* kb = kh + ((size_t)h * 2048 + (kstart + ln)) * 64 + 8 * hi;
  const unsigned short* vb = vt + (size_t)h * 64 * 2048 + (size_t)ln * 2048 + kstart + 8 * hi;
  const uint2* bp = (const uint2*)bmG + ((size_t)h * 512 + (size_t)ks * 128 + hi) * 2048 + j0 + ln;
  // chunk c at iter it lives at bp + (it*8 + 2c)*2048

  f32x16 o0 = {}, o1 = {};
  float mrun = -3.0e38f, lrun = 0.f;

  uint2 bnx1[4], bnx2[4];
#pragma unroll
  for (int c = 0; c < 4; c++) bnx1[c] = bp[(size_t)(2 * c) * 2048];
#pragma unroll
  for (int c = 0; c < 4; c++) bnx2[c] = bp[(size_t)(8 + 2 * c) * 2048];

  for (int it = 0; it < 16; ++it) {
    uint2 bcur[4];
#pragma unroll
    for (int c = 0; c < 4; c++) bcur[c] = bnx1[c];
#pragma unroll
    for (int c = 0; c < 4; c++) bnx1[c] = bnx2[c];
    if (it + 2 < 16) {
#pragma unroll
      for (int c = 0; c < 4; c++) bnx2[c] = bp[(size_t)((it + 2) * 8 + 2 * c) * 2048];
    }
    s16x8 kf[4], vf[4];
    {
      const unsigned short* kp = kb + (size_t)it * (32 * 64);
#pragma unroll
      for (int ds = 0; ds < 4; ds++) kf[ds] = *(const s16x8*)(kp + ds * 16);
      const unsigned short* vp = vb + (size_t)it * 32;
      vf[0] = *(const s16x8*)(vp);
      vf[1] = *(const s16x8*)(vp + 32 * 2048);
      vf[2] = *(const s16x8*)(vp + 16);
      vf[3] = *(const s16x8*)(vp + 32 * 2048 + 16);
    }
    // S^T = K*Q^T : reg r -> kl=(r&3)+8*(r>>2)+4*hi, lane ln -> j
    f32x16 st = {};
#pragma unroll
    for (int ds = 0; ds < 4; ds++)
      st = __builtin_amdgcn_mfma_f32_32x32x16_bf16(kf[ds], qf[ds], st, 0, 0, 0);
    float p[16];
    float tmax = -3.0e38f;
#pragma unroll
    for (int r = 0; r < 16; r++) {
      const unsigned word = (r & 2) ? bcur[r >> 2].y : bcur[r >> 2].x;
      const unsigned short u = (r & 1) ? (unsigned short)(word >> 16) : (unsigned short)(word & 0xffffu);
      const float sv = st[r] * 0.125f + bf2f(u);
      p[r] = sv;
      tmax = fmaxf(tmax, sv);
    }
    tmax = fmaxf(tmax, __shfl_xor(tmax, 32));
    const float mnew = fmaxf(mrun, tmax);
    const float sc = __expf(mrun - mnew);
    float psum = 0.f;
#pragma unroll
    for (int r = 0; r < 16; r++) { p[r] = __expf(p[r] - mnew); psum += p[r]; }
    psum += __shfl_xor(psum, 32);
    lrun = lrun * sc + psum;
    mrun = mnew;
#pragma unroll
    for (int r = 0; r < 16; r++) {
      const int jj = (r & 3) + 8 * (r >> 2) + 4 * hi;
      const float s2 = __shfl(sc, jj);
      o0[r] *= s2;
      o1[r] *= s2;
    }
    unsigned pk[8];
#pragma unroll
    for (int q = 0; q < 8; q++)
      pk[q] = (unsigned)f2bf(p[2 * q]) | ((unsigned)f2bf(p[2 * q + 1]) << 16);
#pragma unroll
    for (int s = 0; s < 2; s++) {
      const unsigned a0 = pk[4 * s + 0], a1 = pk[4 * s + 1];
      const unsigned a2 = pk[4 * s + 2], a3 = pk[4 * s + 3];
      const unsigned x0 = (unsigned)__shfl_xor((int)a0, 32);
      const unsigned x1 = (unsigned)__shfl_xor((int)a1, 32);
      const unsigned x2 = (unsigned)__shfl_xor((int)a2, 32);
      const unsigned x3 = (unsigned)__shfl_xor((int)a3, 32);
      union { int4 i; s16x8 v; } u;
      u.i.x = (int)(hi ? x2 : a0);
      u.i.y = (int)(hi ? x3 : a1);
      u.i.z = (int)(hi ? a2 : x0);
      u.i.w = (int)(hi ? a3 : x1);
      o0 = __builtin_amdgcn_mfma_f32_32x32x16_bf16(u.v, vf[2 * s + 0], o0, 0, 0, 0);
      o1 = __builtin_amdgcn_mfma_f32_32x32x16_bf16(u.v, vf[2 * s + 1], o1, 0, 0, 0);
    }
  }

  // Opart layout [ks][jt][h][j32][d64], ML [ks][jt][h][j32][2]
  float* ob = Opart + (((size_t)(ks * 64 + jt) * 16 + h) * 32) * 64;
#pragma unroll
  for (int r = 0; r < 16; r++) {
    const int jj = (r & 3) + 8 * (r >> 2) + 4 * hi;
    ob[(size_t)jj * 64 + ln] = o0[r];
    ob[(size_t)jj * 64 + 32 + ln] = o1[r];
  }
  if (hi == 0) {
    float* mlp = ML + (((size_t)(ks * 64 + jt) * 16 + h) * 32 + ln) * 2;
    mlp[0] = mrun;
    mlp[1] = lrun;
  }
}

// ---------------------------------------------------------------- combine k-splits -> attn_flat bf16 [2048][1024]
__global__ void k_combine(const float* __restrict__ Opart, const float* __restrict__ ML,
                          unsigned short* __restrict__ attn_flat) {
  const int j = blockIdx.x, t = threadIdx.x;
  const int jt = j >> 5, jl = j & 31;
  const int d = t >> 2;
  unsigned short tmp[4];
#pragma unroll
  for (int q = 0; q < 4; q++) {
    const int hh = 4 * (t & 3) + q;
    float m[4], lv[4];
#pragma unroll
    for (int ksi = 0; ksi < 4; ksi++) {
      const size_t base = ((size_t)(ksi * 64 + jt) * 16 + hh) * 32 + jl;
      m[ksi] = ML[base * 2];
      lv[ksi] = ML[base * 2 + 1];
    }
    const float M = fmaxf(fmaxf(m[0], m[1]), fmaxf(m[2], m[3]));
    float L = 0.f, acc = 0.f;
#pragma unroll
    for (int ksi = 0; ksi < 4; ksi++) {
      const float e = __expf(m[ksi] - M);
      L += lv[ksi] * e;
      const size_t base = ((size_t)(ksi * 64 + jt) * 16 + hh) * 32 + jl;
      acc += Opart[base * 64 + d] * e;
    }
    tmp[q] = f2bf(acc / L);
  }
  ushort4 outv;
  outv.x = tmp[0]; outv.y = tmp[1]; outv.z = tmp[2]; outv.w = tmp[3];
  *(ushort4*)(attn_flat + (size_t)j * 1024 + t * 4) = outv;
}

// ---------------------------------------------------------------- launch
extern "C" void kernel_launch(void* const* d_in, const int* in_sizes, int n_in,
                              void* d_out, int out_size, void* d_ws, size_t ws_size,
                              hipStream_t stream) {
  const float* x     = (const float*)d_in[0];
  const float* bias  = (const float*)d_in[1];
  const int*   mask  = (const int*)d_in[2];
  const float* w_qkv = (const float*)d_in[3];
  const float* b_qkv = (const float*)d_in[4];
  const float* w_out = (const float*)d_in[5];
  const float* b_out = (const float*)d_in[6];
  float* out = (float*)d_out;

  char* ws = (char*)d_ws;
  unsigned short* xb   = (unsigned short*)(ws);                      // 4 MB
  unsigned short* wqb  = (unsigned short*)(ws + ((size_t)4 << 20));  // 6 MB
  unsigned short* wob  = (unsigned short*)(ws + ((size_t)10 << 20)); // 2 MB
  float* cost          = (float*)(ws + ((size_t)12 << 20));
  float* sint          = (float*)(ws + ((size_t)12 << 20) + (256 << 10));
  float* qkv           = (float*)(ws + ((size_t)13 << 20));          // 24 MB
  unsigned short* qhp  = (unsigned short*)(ws + ((size_t)37 << 20)); // 4 MB
  unsigned short* khp  = (unsigned short*)(ws + ((size_t)41 << 20)); // 4 MB
  unsigned short* vtp  = (unsigned short*)(ws + ((size_t)45 << 20)); // 4 MB
  unsigned short* af   = (unsigned short*)(ws + ((size_t)49 << 20)); // 4 MB
  float* Opart         = (float*)(ws + ((size_t)53 << 20));          // 33.6 MB
  float* ML            = (float*)(ws + ((size_t)88 << 20));          // 1 MB
  unsigned short* bmG  = (unsigned short*)(ws + ((size_t)90 << 20)); // 128 MB

  k_cvt_bf16<<<dim3(512), dim3(256), 0, stream>>>(x, xb, 2048 * 1024 / 4);
  k_cvt_bf16<<<dim3(512), dim3(256), 0, stream>>>(w_qkv, wqb, 3072 * 1024 / 4);
  k_cvt_bf16<<<dim3(512), dim3(256), 0, stream>>>(w_out, wob, 1024 * 1024 / 4);
  k_rope_table<<<dim3(256), dim3(256), 0, stream>>>(cost, sint);
  k_prep<<<dim3(128, 8), dim3(256), 0, stream>>>(bias, mask, bmG);
  k_gemm_bt<<<dim3(16, 24), dim3(256), 0, stream>>>(xb, wqb, b_qkv, qkv, 2048, 3072, 1024);
  k_rope_relayout<<<dim3(2048), dim3(256), 0, stream>>>(qkv, cost, sint, qhp, khp, vtp);
  k_attn<<<dim3(4, 64, 4), dim3(256), 0, stream>>>(bmG, qhp, khp, vtp, Opart, ML);
  k_combine<<<dim3(2048), dim3(256), 0, stream>>>(Opart, ML, af);
  k_gemm_bt<<<dim3(16, 8), dim3(256), 0, stream>>>(af, wob, b_out, out, 2048, 1024, 1024);
}

// Round 7
// 353.188 us; speedup vs baseline: 1.3152x; 1.3152x over previous
//
#include <hip/hip_runtime.h>
#include <stdint.h>
#include <math.h>

using f32x4  = __attribute__((ext_vector_type(4)))  float;
using f32x16 = __attribute__((ext_vector_type(16))) float;
using s16x8  = __attribute__((ext_vector_type(8)))  short;

#define DI __device__ __forceinline__

DI unsigned short f2bf(float f) {
  unsigned u = __float_as_uint(f);
  u += 0x7FFFu + ((u >> 16) & 1u);
  return (unsigned short)(u >> 16);
}
DI float bf2f(unsigned short h) { return __uint_as_float((unsigned)h << 16); }

// ---------------------------------------------------------------- f32 -> bf16
__global__ void k_cvt_bf16(const float* __restrict__ in, unsigned short* __restrict__ out, int n4) {
  int i = blockIdx.x * blockDim.x + threadIdx.x;
  const int stride = gridDim.x * blockDim.x;
  for (; i < n4; i += stride) {
    float4 v = reinterpret_cast<const float4*>(in)[i];
    ushort4 o;
    o.x = f2bf(v.x); o.y = f2bf(v.y); o.z = f2bf(v.z); o.w = f2bf(v.w);
    reinterpret_cast<ushort4*>(out)[i] = o;
  }
}

// ---------------------------------------------------------------- rope tables (2048 x 32)
__global__ void k_rope_table(float* __restrict__ cost, float* __restrict__ sint) {
  const int idx = blockIdx.x * 256 + threadIdx.x;  // 65536
  const int s = idx >> 5, fi = idx & 31;
  const double invf = pow(10000.0, -(double)fi / 32.0);
  const float ang = (float)s * (float)invf;
  cost[idx] = (float)cos((double)ang);
  sint[idx] = (float)sin((double)ang);
}

// ---------------------------------------------------------------- bf16 GEMM  C[M][N] = A[M][K]*B[N][K]^T + bias
__global__ __launch_bounds__(256) void k_gemm_bt(
    const unsigned short* __restrict__ A, const unsigned short* __restrict__ B,
    const float* __restrict__ bias, float* __restrict__ C, int M, int N, int K) {
  __shared__ unsigned short As[128 * 32], Bs[128 * 32];
  const int tid = threadIdx.x, l = tid & 63, w = tid >> 6;
  const int wr = w >> 1, wc = w & 1;
  const int m0 = blockIdx.x * 128, n0 = blockIdx.y * 128;
  const int srow = tid >> 2, scol = (tid & 3) * 8;
  f32x4 acc[4][4] = {};
  for (int k0 = 0; k0 < K; k0 += 32) {
    s16x8 a0 = *(const s16x8*)(A + (size_t)(m0 + srow) * K + k0 + scol);
    s16x8 a1 = *(const s16x8*)(A + (size_t)(m0 + 64 + srow) * K + k0 + scol);
    s16x8 b0 = *(const s16x8*)(B + (size_t)(n0 + srow) * K + k0 + scol);
    s16x8 b1 = *(const s16x8*)(B + (size_t)(n0 + 64 + srow) * K + k0 + scol);
    __syncthreads();
    *(s16x8*)&As[srow * 32 + scol] = a0;
    *(s16x8*)&As[(64 + srow) * 32 + scol] = a1;
    *(s16x8*)&Bs[srow * 32 + scol] = b0;
    *(s16x8*)&Bs[(64 + srow) * 32 + scol] = b1;
    __syncthreads();
    s16x8 af[4], bf[4];
#pragma unroll
    for (int i = 0; i < 4; i++)
      af[i] = *(const s16x8*)&As[(wr * 64 + i * 16 + (l & 15)) * 32 + (l >> 4) * 8];
#pragma unroll
    for (int j = 0; j < 4; j++)
      bf[j] = *(const s16x8*)&Bs[(wc * 64 + j * 16 + (l & 15)) * 32 + (l >> 4) * 8];
#pragma unroll
    for (int i = 0; i < 4; i++)
#pragma unroll
      for (int j = 0; j < 4; j++)
        acc[i][j] = __builtin_amdgcn_mfma_f32_16x16x32_bf16(af[i], bf[j], acc[i][j], 0, 0, 0);
  }
#pragma unroll
  for (int i = 0; i < 4; i++) {
    const int row = m0 + wr * 64 + i * 16 + (l >> 4) * 4;
#pragma unroll
    for (int j = 0; j < 4; j++) {
      const int col = n0 + wc * 64 + j * 16 + (l & 15);
      const float bv = bias ? bias[col] : 0.f;
#pragma unroll
      for (int r = 0; r < 4; r++) C[(size_t)(row + r) * N + col] = acc[i][j][r] + bv;
    }
  }
}

// ---------------------------------------------------------------- RoPE + relayout
// rotate_half pairs heads h^8 (sign - for h<8); tables indexed by (s, d&31).
__global__ void k_rope_relayout(const float* __restrict__ qkv, const float* __restrict__ cost,
                                const float* __restrict__ sint,
                                unsigned short* __restrict__ qh, unsigned short* __restrict__ kh,
                                unsigned short* __restrict__ vt) {
  const int s = blockIdx.x, t = threadIdx.x;
  const float* row = qkv + (size_t)s * 3072;
  const int c = t * 4;
  const int d = c >> 4;
  const int hbase = c & 15;
  const float cv = cost[s * 32 + (d & 31)];
  const float sv = sint[s * 32 + (d & 31)];
  const float sgn = (hbase < 8) ? -1.f : 1.f;
  {
    float4 v = *(const float4*)(row + c);
    float4 v2 = *(const float4*)(row + (c ^ 8));
    const float* vp = (const float*)&v;
    const float* vp2 = (const float*)&v2;
#pragma unroll
    for (int i = 0; i < 4; i++) {
      float val = vp[i] * cv + sgn * vp2[i] * sv;
      qh[(size_t)(hbase + i) * (2048 * 64) + s * 64 + d] = f2bf(val);
    }
  }
  {
    float4 v = *(const float4*)(row + 1024 + c);
    float4 v2 = *(const float4*)(row + 1024 + (c ^ 8));
    const float* vp = (const float*)&v;
    const float* vp2 = (const float*)&v2;
#pragma unroll
    for (int i = 0; i < 4; i++) {
      float val = vp[i] * cv + sgn * vp2[i] * sv;
      kh[(size_t)(hbase + i) * (2048 * 64) + s * 64 + d] = f2bf(val);
    }
  }
  {
    float4 v = *(const float4*)(row + 2048 + c);
    const float* vp = (const float*)&v;
#pragma unroll
    for (int i = 0; i < 4; i++)
      vt[(size_t)(hbase + i) * (64 * 2048) + (size_t)d * 2048 + s] = f2bf(vp[i]);
  }
}

// ---------------------------------------------------------------- bias+mask pre-pass v4
// Per-WAVE barrier-free global_load_lds pipeline.
// in : bias fp32 [j][k][h16], mask int32 same
// out: bmG bf16 [h][ko=k/4][j][ki=k%4]
// Wave owns j16 tile; chunk = k4 (4KB bias + 4KB mask per buffer, dbuf).
// LDS image per chunk: rows j(16) x 16 slots of 16B; slot p of row j holds
// logical (k = q>>2, hb = q&3) with q = p ^ j  (pre-swizzled SOURCE gather ->
// transpose-read banks spread). Stores: lane->j, 128B contiguous per h-word.
#define GLDS(gp, lp)                                                          \
  __builtin_amdgcn_global_load_lds(                                           \
      (const __attribute__((address_space(1))) unsigned int*)(const void*)(gp), \
      (__attribute__((address_space(3))) unsigned int*)(void*)(lp), 16, 0, 0)

__global__ __launch_bounds__(256) void k_prep(const float* __restrict__ bias,
                                              const int* __restrict__ mask,
                                              unsigned short* __restrict__ bmG) {
  __shared__ float smem[2][4][2][1024];  // [buf][wave][bias|mask][4KB]
  const int tid = threadIdx.x, w = tid >> 6, l = tid & 63;
  const int jp_l = l >> 4;   // 0..3, row within instr group
  const int p_l = l & 15;    // slot
  const int j_r = l & 15;    // consume: row
  const int hq = l >> 4;     // consume: h quad
  const int jt = blockIdx.x, ks = blockIdx.y;  // grid (32, 16)
  const int jb = jt * 64 + w * 16;
  const int kb = ks * 128;  // 32 chunks of k4

#define PREP_ISSUE(BUF, KC)                                                       \
  {                                                                               \
    _Pragma("unroll") for (int i = 0; i < 4; ++i) {                               \
      const int jp = 4 * i + jp_l;                                                \
      const int q = p_l ^ jp;                                                     \
      const size_t e = ((size_t)(jb + jp) * 2048 + (KC) + (q >> 2)) * 16 + (q & 3) * 4; \
      GLDS(bias + e, &smem[BUF][w][0][i * 256]);                                  \
      GLDS(mask + e, &smem[BUF][w][1][i * 256]);                                  \
    }                                                                             \
  }

  PREP_ISSUE(0, kb)

  for (int cc = 0; cc < 32; ++cc) {
    const int buf = cc & 1;
    if (cc + 1 < 32) {
      PREP_ISSUE(buf ^ 1, kb + (cc + 1) * 4)
      asm volatile("s_waitcnt vmcnt(8)" ::: "memory");
    } else {
      asm volatile("s_waitcnt vmcnt(0)" ::: "memory");
    }
    const float* bsm = &smem[buf][w][0][0];
    const int* msm = (const int*)&smem[buf][w][1][0];
    const int ko = ks * 32 + cc;
#pragma unroll
    for (int bp = 0; bp < 2; ++bp) {
      float fe[2][4];
#pragma unroll
      for (int ki = 0; ki < 4; ++ki) {
        const int r = ki * 4 + hq;
        const int p = r ^ j_r;
        const int a8 = j_r * 32 + p * 2 + bp;  // 8B units
        float2 bvv = *(const float2*)(bsm + a8 * 2);
        int2 mvv = *(const int2*)(msm + a8 * 2);
        fe[0][ki] = mvv.x ? bvv.x : -1.0e8f;
        fe[1][ki] = mvv.y ? bvv.y : -1.0e8f;
      }
#pragma unroll
      for (int e = 0; e < 2; ++e) {
        const int h = 4 * hq + 2 * bp + e;
        uint2 o;
        o.x = (unsigned)f2bf(fe[e][0]) | ((unsigned)f2bf(fe[e][1]) << 16);
        o.y = (unsigned)f2bf(fe[e][2]) | ((unsigned)f2bf(fe[e][3]) << 16);
        *(uint2*)(bmG + ((size_t)(h * 512 + ko) * 2048 + jb + j_r) * 4) = o;
      }
    }
  }
#undef PREP_ISSUE
}

// ---------------------------------------------------------------- attention (barrier-free)
// grid (q4=4, jt=64, ks=4), 256 threads = 4 waves, 1 head/wave, 32 q-rows, 512 k per block
__global__ __launch_bounds__(256, 4) void k_attn(
    const unsigned short* __restrict__ bmG,
    const unsigned short* __restrict__ qh, const unsigned short* __restrict__ kh,
    const unsigned short* __restrict__ vt,
    float* __restrict__ Opart, float* __restrict__ ML) {
  const int tid = threadIdx.x, l = tid & 63, w = tid >> 6;
  const int hi = l >> 5, ln = l & 31;
  const int q4 = blockIdx.x, jt = blockIdx.y, ks = blockIdx.z;
  const int j0 = jt * 32, h = q4 * 4 + w, kstart = ks * 512;

  s16x8 qf[4];
  {
    const unsigned short* qb = qh + ((size_t)h * 2048 + (j0 + ln)) * 64 + 8 * hi;
#pragma unroll
    for (int ds = 0; ds < 4; ds++) qf[ds] = *(const s16x8*)(qb + ds * 16);
  }
  const unsigned short* kb = kh + ((size_t)h * 2048 + (kstart + ln)) * 64 + 8 * hi;
  const unsigned short* vb = vt + (size_t)h * 64 * 2048 + (size_t)ln * 2048 + kstart + 8 * hi;
  const uint2* bp = (const uint2*)bmG + ((size_t)h * 512 + (size_t)ks * 128 + hi) * 2048 + j0 + ln;
  // chunk c at iter it lives at bp + (it*8 + 2c)*2048

  f32x16 o0 = {}, o1 = {};
  float mrun = -3.0e38f, lrun = 0.f;

  uint2 bnx1[4], bnx2[4];
#pragma unroll
  for (int c = 0; c < 4; c++) bnx1[c] = bp[(size_t)(2 * c) * 2048];
#pragma unroll
  for (int c = 0; c < 4; c++) bnx2[c] = bp[(size_t)(8 + 2 * c) * 2048];

  for (int it = 0; it < 16; ++it) {
    uint2 bcur[4];
#pragma unroll
    for (int c = 0; c < 4; c++) bcur[c] = bnx1[c];
#pragma unroll
    for (int c = 0; c < 4; c++) bnx1[c] = bnx2[c];
    if (it + 2 < 16) {
#pragma unroll
      for (int c = 0; c < 4; c++) bnx2[c] = bp[(size_t)((it + 2) * 8 + 2 * c) * 2048];
    }
    s16x8 kf[4], vf[4];
    {
      const unsigned short* kp = kb + (size_t)it * (32 * 64);
#pragma unroll
      for (int ds = 0; ds < 4; ds++) kf[ds] = *(const s16x8*)(kp + ds * 16);
      const unsigned short* vp = vb + (size_t)it * 32;
      vf[0] = *(const s16x8*)(vp);
      vf[1] = *(const s16x8*)(vp + 32 * 2048);
      vf[2] = *(const s16x8*)(vp + 16);
      vf[3] = *(const s16x8*)(vp + 32 * 2048 + 16);
    }
    // S^T = K*Q^T : reg r -> kl=(r&3)+8*(r>>2)+4*hi, lane ln -> j
    f32x16 st = {};
#pragma unroll
    for (int ds = 0; ds < 4; ds++)
      st = __builtin_amdgcn_mfma_f32_32x32x16_bf16(kf[ds], qf[ds], st, 0, 0, 0);
    float p[16];
    float tmax = -3.0e38f;
#pragma unroll
    for (int r = 0; r < 16; r++) {
      const unsigned word = (r & 2) ? bcur[r >> 2].y : bcur[r >> 2].x;
      const unsigned short u = (r & 1) ? (unsigned short)(word >> 16) : (unsigned short)(word & 0xffffu);
      const float sv = st[r] * 0.125f + bf2f(u);
      p[r] = sv;
      tmax = fmaxf(tmax, sv);
    }
    tmax = fmaxf(tmax, __shfl_xor(tmax, 32));
    const float mnew = fmaxf(mrun, tmax);
    const float sc = __expf(mrun - mnew);
    float psum = 0.f;
#pragma unroll
    for (int r = 0; r < 16; r++) { p[r] = __expf(p[r] - mnew); psum += p[r]; }
    psum += __shfl_xor(psum, 32);
    lrun = lrun * sc + psum;
    mrun = mnew;
#pragma unroll
    for (int r = 0; r < 16; r++) {
      const int jj = (r & 3) + 8 * (r >> 2) + 4 * hi;
      const float s2 = __shfl(sc, jj);
      o0[r] *= s2;
      o1[r] *= s2;
    }
    unsigned pk[8];
#pragma unroll
    for (int q = 0; q < 8; q++)
      pk[q] = (unsigned)f2bf(p[2 * q]) | ((unsigned)f2bf(p[2 * q + 1]) << 16);
#pragma unroll
    for (int s = 0; s < 2; s++) {
      const unsigned a0 = pk[4 * s + 0], a1 = pk[4 * s + 1];
      const unsigned a2 = pk[4 * s + 2], a3 = pk[4 * s + 3];
      const unsigned x0 = (unsigned)__shfl_xor((int)a0, 32);
      const unsigned x1 = (unsigned)__shfl_xor((int)a1, 32);
      const unsigned x2 = (unsigned)__shfl_xor((int)a2, 32);
      const unsigned x3 = (unsigned)__shfl_xor((int)a3, 32);
      union { int4 i; s16x8 v; } u;
      u.i.x = (int)(hi ? x2 : a0);
      u.i.y = (int)(hi ? x3 : a1);
      u.i.z = (int)(hi ? a2 : x0);
      u.i.w = (int)(hi ? a3 : x1);
      o0 = __builtin_amdgcn_mfma_f32_32x32x16_bf16(u.v, vf[2 * s + 0], o0, 0, 0, 0);
      o1 = __builtin_amdgcn_mfma_f32_32x32x16_bf16(u.v, vf[2 * s + 1], o1, 0, 0, 0);
    }
  }

  // Opart layout [ks][jt][h][j32][d64], ML [ks][jt][h][j32][2]
  float* ob = Opart + (((size_t)(ks * 64 + jt) * 16 + h) * 32) * 64;
#pragma unroll
  for (int r = 0; r < 16; r++) {
    const int jj = (r & 3) + 8 * (r >> 2) + 4 * hi;
    ob[(size_t)jj * 64 + ln] = o0[r];
    ob[(size_t)jj * 64 + 32 + ln] = o1[r];
  }
  if (hi == 0) {
    float* mlp = ML + (((size_t)(ks * 64 + jt) * 16 + h) * 32 + ln) * 2;
    mlp[0] = mrun;
    mlp[1] = lrun;
  }
}

// ---------------------------------------------------------------- combine k-splits -> attn_flat bf16 [2048][1024]
__global__ void k_combine(const float* __restrict__ Opart, const float* __restrict__ ML,
                          unsigned short* __restrict__ attn_flat) {
  const int j = blockIdx.x, t = threadIdx.x;
  const int jt = j >> 5, jl = j & 31;
  const int d = t >> 2;
  unsigned short tmp[4];
#pragma unroll
  for (int q = 0; q < 4; q++) {
    const int hh = 4 * (t & 3) + q;
    float m[4], lv[4];
#pragma unroll
    for (int ksi = 0; ksi < 4; ksi++) {
      const size_t base = ((size_t)(ksi * 64 + jt) * 16 + hh) * 32 + jl;
      m[ksi] = ML[base * 2];
      lv[ksi] = ML[base * 2 + 1];
    }
    const float M = fmaxf(fmaxf(m[0], m[1]), fmaxf(m[2], m[3]));
    float L = 0.f, acc = 0.f;
#pragma unroll
    for (int ksi = 0; ksi < 4; ksi++) {
      const float e = __expf(m[ksi] - M);
      L += lv[ksi] * e;
      const size_t base = ((size_t)(ksi * 64 + jt) * 16 + hh) * 32 + jl;
      acc += Opart[base * 64 + d] * e;
    }
    tmp[q] = f2bf(acc / L);
  }
  ushort4 outv;
  outv.x = tmp[0]; outv.y = tmp[1]; outv.z = tmp[2]; outv.w = tmp[3];
  *(ushort4*)(attn_flat + (size_t)j * 1024 + t * 4) = outv;
}

// ---------------------------------------------------------------- launch
extern "C" void kernel_launch(void* const* d_in, const int* in_sizes, int n_in,
                              void* d_out, int out_size, void* d_ws, size_t ws_size,
                              hipStream_t stream) {
  const float* x     = (const float*)d_in[0];
  const float* bias  = (const float*)d_in[1];
  const int*   mask  = (const int*)d_in[2];
  const float* w_qkv = (const float*)d_in[3];
  const float* b_qkv = (const float*)d_in[4];
  const float* w_out = (const float*)d_in[5];
  const float* b_out = (const float*)d_in[6];
  float* out = (float*)d_out;

  char* ws = (char*)d_ws;
  unsigned short* xb   = (unsigned short*)(ws);                      // 4 MB
  unsigned short* wqb  = (unsigned short*)(ws + ((size_t)4 << 20));  // 6 MB
  unsigned short* wob  = (unsigned short*)(ws + ((size_t)10 << 20)); // 2 MB
  float* cost          = (float*)(ws + ((size_t)12 << 20));
  float* sint          = (float*)(ws + ((size_t)12 << 20) + (256 << 10));
  float* qkv           = (float*)(ws + ((size_t)13 << 20));          // 24 MB
  unsigned short* qhp  = (unsigned short*)(ws + ((size_t)37 << 20)); // 4 MB
  unsigned short* khp  = (unsigned short*)(ws + ((size_t)41 << 20)); // 4 MB
  unsigned short* vtp  = (unsigned short*)(ws + ((size_t)45 << 20)); // 4 MB
  unsigned short* af   = (unsigned short*)(ws + ((size_t)49 << 20)); // 4 MB
  float* Opart         = (float*)(ws + ((size_t)53 << 20));          // 33.6 MB
  float* ML            = (float*)(ws + ((size_t)88 << 20));          // 1 MB
  unsigned short* bmG  = (unsigned short*)(ws + ((size_t)90 << 20)); // 128 MB

  k_cvt_bf16<<<dim3(512), dim3(256), 0, stream>>>(x, xb, 2048 * 1024 / 4);
  k_cvt_bf16<<<dim3(512), dim3(256), 0, stream>>>(w_qkv, wqb, 3072 * 1024 / 4);
  k_cvt_bf16<<<dim3(512), dim3(256), 0, stream>>>(w_out, wob, 1024 * 1024 / 4);
  k_rope_table<<<dim3(256), dim3(256), 0, stream>>>(cost, sint);
  k_prep<<<dim3(32, 16), dim3(256), 0, stream>>>(bias, mask, bmG);
  k_gemm_bt<<<dim3(16, 24), dim3(256), 0, stream>>>(xb, wqb, b_qkv, qkv, 2048, 3072, 1024);
  k_rope_relayout<<<dim3(2048), dim3(256), 0, stream>>>(qkv, cost, sint, qhp, khp, vtp);
  k_attn<<<dim3(4, 64, 4), dim3(256), 0, stream>>>(bmG, qhp, khp, vtp, Opart, ML);
  k_combine<<<dim3(2048), dim3(256), 0, stream>>>(Opart, ML, af);
  k_gemm_bt<<<dim3(16, 8), dim3(256), 0, stream>>>(af, wob, b_out, out, 2048, 1024, 1024);
}

// Round 8
// 352.504 us; speedup vs baseline: 1.3177x; 1.0019x over previous
//
#include <hip/hip_runtime.h>
#include <stdint.h>
#include <math.h>

using f32x4  = __attribute__((ext_vector_type(4)))  float;
using f32x16 = __attribute__((ext_vector_type(16))) float;
using s16x8  = __attribute__((ext_vector_type(8)))  short;

#define DI __device__ __forceinline__

DI unsigned short f2bf(float f) {
  unsigned u = __float_as_uint(f);
  u += 0x7FFFu + ((u >> 16) & 1u);
  return (unsigned short)(u >> 16);
}
DI float bf2f(unsigned short h) { return __uint_as_float((unsigned)h << 16); }

// ---------------------------------------------------------------- f32 -> bf16
__global__ void k_cvt_bf16(const float* __restrict__ in, unsigned short* __restrict__ out, int n4) {
  int i = blockIdx.x * blockDim.x + threadIdx.x;
  const int stride = gridDim.x * blockDim.x;
  for (; i < n4; i += stride) {
    float4 v = reinterpret_cast<const float4*>(in)[i];
    ushort4 o;
    o.x = f2bf(v.x); o.y = f2bf(v.y); o.z = f2bf(v.z); o.w = f2bf(v.w);
    reinterpret_cast<ushort4*>(out)[i] = o;
  }
}

// ---------------------------------------------------------------- rope tables (2048 x 32)
__global__ void k_rope_table(float* __restrict__ cost, float* __restrict__ sint) {
  const int idx = blockIdx.x * 256 + threadIdx.x;  // 65536
  const int s = idx >> 5, fi = idx & 31;
  const double invf = pow(10000.0, -(double)fi / 32.0);
  const float ang = (float)s * (float)invf;
  cost[idx] = (float)cos((double)ang);
  sint[idx] = (float)sin((double)ang);
}

// ---------------------------------------------------------------- bf16 GEMM  C[M][N] = A[M][K]*B[N][K]^T + bias
__global__ __launch_bounds__(256) void k_gemm_bt(
    const unsigned short* __restrict__ A, const unsigned short* __restrict__ B,
    const float* __restrict__ bias, float* __restrict__ C, int M, int N, int K) {
  __shared__ unsigned short As[128 * 32], Bs[128 * 32];
  const int tid = threadIdx.x, l = tid & 63, w = tid >> 6;
  const int wr = w >> 1, wc = w & 1;
  const int m0 = blockIdx.x * 128, n0 = blockIdx.y * 128;
  const int srow = tid >> 2, scol = (tid & 3) * 8;
  f32x4 acc[4][4] = {};
  for (int k0 = 0; k0 < K; k0 += 32) {
    s16x8 a0 = *(const s16x8*)(A + (size_t)(m0 + srow) * K + k0 + scol);
    s16x8 a1 = *(const s16x8*)(A + (size_t)(m0 + 64 + srow) * K + k0 + scol);
    s16x8 b0 = *(const s16x8*)(B + (size_t)(n0 + srow) * K + k0 + scol);
    s16x8 b1 = *(const s16x8*)(B + (size_t)(n0 + 64 + srow) * K + k0 + scol);
    __syncthreads();
    *(s16x8*)&As[srow * 32 + scol] = a0;
    *(s16x8*)&As[(64 + srow) * 32 + scol] = a1;
    *(s16x8*)&Bs[srow * 32 + scol] = b0;
    *(s16x8*)&Bs[(64 + srow) * 32 + scol] = b1;
    __syncthreads();
    s16x8 af[4], bf[4];
#pragma unroll
    for (int i = 0; i < 4; i++)
      af[i] = *(const s16x8*)&As[(wr * 64 + i * 16 + (l & 15)) * 32 + (l >> 4) * 8];
#pragma unroll
    for (int j = 0; j < 4; j++)
      bf[j] = *(const s16x8*)&Bs[(wc * 64 + j * 16 + (l & 15)) * 32 + (l >> 4) * 8];
#pragma unroll
    for (int i = 0; i < 4; i++)
#pragma unroll
      for (int j = 0; j < 4; j++)
        acc[i][j] = __builtin_amdgcn_mfma_f32_16x16x32_bf16(af[i], bf[j], acc[i][j], 0, 0, 0);
  }
#pragma unroll
  for (int i = 0; i < 4; i++) {
    const int row = m0 + wr * 64 + i * 16 + (l >> 4) * 4;
#pragma unroll
    for (int j = 0; j < 4; j++) {
      const int col = n0 + wc * 64 + j * 16 + (l & 15);
      const float bv = bias ? bias[col] : 0.f;
#pragma unroll
      for (int r = 0; r < 4; r++) C[(size_t)(row + r) * N + col] = acc[i][j][r] + bv;
    }
  }
}

// ---------------------------------------------------------------- RoPE + relayout
// rotate_half pairs heads h^8 (sign - for h<8); tables indexed by (s, d&31).
__global__ void k_rope_relayout(const float* __restrict__ qkv, const float* __restrict__ cost,
                                const float* __restrict__ sint,
                                unsigned short* __restrict__ qh, unsigned short* __restrict__ kh,
                                unsigned short* __restrict__ vt) {
  const int s = blockIdx.x, t = threadIdx.x;
  const float* row = qkv + (size_t)s * 3072;
  const int c = t * 4;
  const int d = c >> 4;
  const int hbase = c & 15;
  const float cv = cost[s * 32 + (d & 31)];
  const float sv = sint[s * 32 + (d & 31)];
  const float sgn = (hbase < 8) ? -1.f : 1.f;
  {
    float4 v = *(const float4*)(row + c);
    float4 v2 = *(const float4*)(row + (c ^ 8));
    const float* vp = (const float*)&v;
    const float* vp2 = (const float*)&v2;
#pragma unroll
    for (int i = 0; i < 4; i++) {
      float val = vp[i] * cv + sgn * vp2[i] * sv;
      qh[(size_t)(hbase + i) * (2048 * 64) + s * 64 + d] = f2bf(val);
    }
  }
  {
    float4 v = *(const float4*)(row + 1024 + c);
    float4 v2 = *(const float4*)(row + 1024 + (c ^ 8));
    const float* vp = (const float*)&v;
    const float* vp2 = (const float*)&v2;
#pragma unroll
    for (int i = 0; i < 4; i++) {
      float val = vp[i] * cv + sgn * vp2[i] * sv;
      kh[(size_t)(hbase + i) * (2048 * 64) + s * 64 + d] = f2bf(val);
    }
  }
  {
    float4 v = *(const float4*)(row + 2048 + c);
    const float* vp = (const float*)&v;
#pragma unroll
    for (int i = 0; i < 4; i++)
      vt[(size_t)(hbase + i) * (64 * 2048) + (size_t)d * 2048 + s] = f2bf(vp[i]);
  }
}

// ---------------------------------------------------------------- fused mask+cast (PURE LINEAR stream)
// bm16[j][k][h] = bf16(mask ? bias : -1e8)   -- same linear index as inputs.
__global__ void k_mask(const float* __restrict__ bias, const int* __restrict__ mask,
                       unsigned short* __restrict__ bm16, int n8) {
  int i = blockIdx.x * blockDim.x + threadIdx.x;
  const int stride = gridDim.x * blockDim.x;
  for (; i < n8; i += stride) {
    float4 b0 = reinterpret_cast<const float4*>(bias)[2 * i];
    float4 b1 = reinterpret_cast<const float4*>(bias)[2 * i + 1];
    int4 m0 = reinterpret_cast<const int4*>(mask)[2 * i];
    int4 m1 = reinterpret_cast<const int4*>(mask)[2 * i + 1];
    uint4 o;
    o.x = (unsigned)f2bf(m0.x ? b0.x : -1.0e8f) | ((unsigned)f2bf(m0.y ? b0.y : -1.0e8f) << 16);
    o.y = (unsigned)f2bf(m0.z ? b0.z : -1.0e8f) | ((unsigned)f2bf(m0.w ? b0.w : -1.0e8f) << 16);
    o.z = (unsigned)f2bf(m1.x ? b1.x : -1.0e8f) | ((unsigned)f2bf(m1.y ? b1.y : -1.0e8f) << 16);
    o.w = (unsigned)f2bf(m1.z ? b1.z : -1.0e8f) | ((unsigned)f2bf(m1.w ? b1.w : -1.0e8f) << 16);
    reinterpret_cast<uint4*>(bm16)[i] = o;
  }
}

// ---------------------------------------------------------------- attention v2
// 16 waves/block = all 16 heads; grid (jt=64, ks=4) = 256 blocks (1/CU).
// Per macro-iter (k32): block stages j32 x k32 x h16 bf16 tile (32 KB) from
// bm16 via global_load_lds (2 instrs/wave, XOR-preswizzled source: phys slot
// l of row j holds logical slot l^j), 3-buffer ring, ONE raw s_barrier +
// counted vmcnt(2) per iter -> stage loads stay in flight across the barrier
// and hide under MFMA+softmax of the previous tile.
#define GLDS16(gp, lp)                                                            \
  __builtin_amdgcn_global_load_lds(                                               \
      (const __attribute__((address_space(1))) unsigned int*)(const void*)(gp),   \
      (__attribute__((address_space(3))) unsigned int*)(void*)(lp), 16, 0, 0)

__global__ __launch_bounds__(1024) void k_attn(
    const unsigned short* __restrict__ bm16,
    const unsigned short* __restrict__ qh, const unsigned short* __restrict__ kh,
    const unsigned short* __restrict__ vt,
    float* __restrict__ Opart, float* __restrict__ ML) {
  __shared__ unsigned short tile[3][32][512];  // 96 KB ring
  const int tid = threadIdx.x, l = tid & 63, w = tid >> 6;  // w = head
  const int hi = l >> 5, ln = l & 31;
  const int jt = blockIdx.x, ks = blockIdx.y;
  const int j0 = jt * 32, kstart = ks * 512;

  s16x8 qf[4];
  {
    const unsigned short* qb = qh + ((size_t)w * 2048 + (j0 + ln)) * 64 + 8 * hi;
#pragma unroll
    for (int ds = 0; ds < 4; ds++) qf[ds] = *(const s16x8*)(qb + ds * 16);
  }
  const unsigned short* kb = kh + ((size_t)w * 2048 + (kstart + ln)) * 64 + 8 * hi;
  const unsigned short* vb = vt + (size_t)w * 64 * 2048 + (size_t)ln * 2048 + kstart + 8 * hi;

  // stage helper: wave w stages rows 2w, 2w+1 of macro m into ring buf m%3
  const int jr0 = 2 * w, jr1 = 2 * w + 1;
  const unsigned short* src0 = bm16 + ((size_t)(j0 + jr0) << 15) + (size_t)kstart * 16 + ((l ^ jr0) << 3);
  const unsigned short* src1 = bm16 + ((size_t)(j0 + jr1) << 15) + (size_t)kstart * 16 + ((l ^ jr1) << 3);

#define STAGE(m)                                           \
  {                                                        \
    const int bi_ = (m) % 3;                               \
    GLDS16(src0 + (size_t)(m) * 512, &tile[bi_][jr0][0]);  \
    GLDS16(src1 + (size_t)(m) * 512, &tile[bi_][jr1][0]);  \
  }

  f32x16 o0 = {}, o1 = {};
  float mrun = -3.0e38f, lrun = 0.f;

  STAGE(0)

  for (int m = 0; m < 16; ++m) {
    if (m + 1 < 16) {
      STAGE(m + 1)
      asm volatile("s_waitcnt vmcnt(2)\n\ts_barrier" ::: "memory");
    } else {
      asm volatile("s_waitcnt vmcnt(0)\n\ts_barrier" ::: "memory");
    }
    const int bi = m % 3;
    s16x8 kf[4], vf[4];
    {
      const unsigned short* kp = kb + (size_t)m * (32 * 64);
#pragma unroll
      for (int ds = 0; ds < 4; ds++) kf[ds] = *(const s16x8*)(kp + ds * 16);
      const unsigned short* vp = vb + (size_t)m * 32;
      vf[0] = *(const s16x8*)(vp);
      vf[1] = *(const s16x8*)(vp + 32 * 2048);
      vf[2] = *(const s16x8*)(vp + 16);
      vf[3] = *(const s16x8*)(vp + 32 * 2048 + 16);
    }
    // S^T = K*Q^T : reg r -> kl=(r&3)+8*(r>>2)+4*hi, lane ln -> j
    f32x16 st = {};
#pragma unroll
    for (int ds = 0; ds < 4; ds++)
      st = __builtin_amdgcn_mfma_f32_32x32x16_bf16(kf[ds], qf[ds], st, 0, 0, 0);
    float p[16];
    float tmax = -3.0e38f;
#pragma unroll
    for (int r = 0; r < 16; r++) {
      const int kl = (r & 3) + 8 * (r >> 2) + 4 * hi;
      const int slot = kl * 2 + (w >> 3);
      const unsigned short u = tile[bi][ln][((slot ^ ln) << 3) + (w & 7)];
      const float sv = st[r] * 0.125f + bf2f(u);
      p[r] = sv;
      tmax = fmaxf(tmax, sv);
    }
    tmax = fmaxf(tmax, __shfl_xor(tmax, 32));
    const float mnew = fmaxf(mrun, tmax);
    const float sc = __expf(mrun - mnew);
    float psum = 0.f;
#pragma unroll
    for (int r = 0; r < 16; r++) { p[r] = __expf(p[r] - mnew); psum += p[r]; }
    psum += __shfl_xor(psum, 32);
    lrun = lrun * sc + psum;
    mrun = mnew;
#pragma unroll
    for (int r = 0; r < 16; r++) {
      const int jj = (r & 3) + 8 * (r >> 2) + 4 * hi;
      const float s2 = __shfl(sc, jj);
      o0[r] *= s2;
      o1[r] *= s2;
    }
    unsigned pk[8];
#pragma unroll
    for (int q = 0; q < 8; q++)
      pk[q] = (unsigned)f2bf(p[2 * q]) | ((unsigned)f2bf(p[2 * q + 1]) << 16);
#pragma unroll
    for (int s = 0; s < 2; s++) {
      const unsigned a0 = pk[4 * s + 0], a1 = pk[4 * s + 1];
      const unsigned a2 = pk[4 * s + 2], a3 = pk[4 * s + 3];
      const unsigned x0 = (unsigned)__shfl_xor((int)a0, 32);
      const unsigned x1 = (unsigned)__shfl_xor((int)a1, 32);
      const unsigned x2 = (unsigned)__shfl_xor((int)a2, 32);
      const unsigned x3 = (unsigned)__shfl_xor((int)a3, 32);
      union { int4 i; s16x8 v; } u;
      u.i.x = (int)(hi ? x2 : a0);
      u.i.y = (int)(hi ? x3 : a1);
      u.i.z = (int)(hi ? a2 : x0);
      u.i.w = (int)(hi ? a3 : x1);
      o0 = __builtin_amdgcn_mfma_f32_32x32x16_bf16(u.v, vf[2 * s + 0], o0, 0, 0, 0);
      o1 = __builtin_amdgcn_mfma_f32_32x32x16_bf16(u.v, vf[2 * s + 1], o1, 0, 0, 0);
    }
  }
#undef STAGE

  // Opart layout [ks][jt][h][j32][d64], ML [ks][jt][h][j32][2]
  float* ob = Opart + (((size_t)(ks * 64 + jt) * 16 + w) * 32) * 64;
#pragma unroll
  for (int r = 0; r < 16; r++) {
    const int jj = (r & 3) + 8 * (r >> 2) + 4 * hi;
    ob[(size_t)jj * 64 + ln] = o0[r];
    ob[(size_t)jj * 64 + 32 + ln] = o1[r];
  }
  if (hi == 0) {
    float* mlp = ML + (((size_t)(ks * 64 + jt) * 16 + w) * 32 + ln) * 2;
    mlp[0] = mrun;
    mlp[1] = lrun;
  }
}

// ---------------------------------------------------------------- combine k-splits -> attn_flat bf16 [2048][1024]
__global__ void k_combine(const float* __restrict__ Opart, const float* __restrict__ ML,
                          unsigned short* __restrict__ attn_flat) {
  const int j = blockIdx.x, t = threadIdx.x;
  const int jt = j >> 5, jl = j & 31;
  const int d = t >> 2;
  unsigned short tmp[4];
#pragma unroll
  for (int q = 0; q < 4; q++) {
    const int hh = 4 * (t & 3) + q;
    float m[4], lv[4];
#pragma unroll
    for (int ksi = 0; ksi < 4; ksi++) {
      const size_t base = ((size_t)(ksi * 64 + jt) * 16 + hh) * 32 + jl;
      m[ksi] = ML[base * 2];
      lv[ksi] = ML[base * 2 + 1];
    }
    const float M = fmaxf(fmaxf(m[0], m[1]), fmaxf(m[2], m[3]));
    float L = 0.f, acc = 0.f;
#pragma unroll
    for (int ksi = 0; ksi < 4; ksi++) {
      const float e = __expf(m[ksi] - M);
      L += lv[ksi] * e;
      const size_t base = ((size_t)(ksi * 64 + jt) * 16 + hh) * 32 + jl;
      acc += Opart[base * 64 + d] * e;
    }
    tmp[q] = f2bf(acc / L);
  }
  ushort4 outv;
  outv.x = tmp[0]; outv.y = tmp[1]; outv.z = tmp[2]; outv.w = tmp[3];
  *(ushort4*)(attn_flat + (size_t)j * 1024 + t * 4) = outv;
}

// ---------------------------------------------------------------- launch
extern "C" void kernel_launch(void* const* d_in, const int* in_sizes, int n_in,
                              void* d_out, int out_size, void* d_ws, size_t ws_size,
                              hipStream_t stream) {
  const float* x     = (const float*)d_in[0];
  const float* bias  = (const float*)d_in[1];
  const int*   mask  = (const int*)d_in[2];
  const float* w_qkv = (const float*)d_in[3];
  const float* b_qkv = (const float*)d_in[4];
  const float* w_out = (const float*)d_in[5];
  const float* b_out = (const float*)d_in[6];
  float* out = (float*)d_out;

  char* ws = (char*)d_ws;
  unsigned short* xb   = (unsigned short*)(ws);                      // 4 MB
  unsigned short* wqb  = (unsigned short*)(ws + ((size_t)4 << 20));  // 6 MB
  unsigned short* wob  = (unsigned short*)(ws + ((size_t)10 << 20)); // 2 MB
  float* cost          = (float*)(ws + ((size_t)12 << 20));
  float* sint          = (float*)(ws + ((size_t)12 << 20) + (256 << 10));
  float* qkv           = (float*)(ws + ((size_t)13 << 20));          // 24 MB
  unsigned short* qhp  = (unsigned short*)(ws + ((size_t)37 << 20)); // 4 MB
  unsigned short* khp  = (unsigned short*)(ws + ((size_t)41 << 20)); // 4 MB
  unsigned short* vtp  = (unsigned short*)(ws + ((size_t)45 << 20)); // 4 MB
  unsigned short* af   = (unsigned short*)(ws + ((size_t)49 << 20)); // 4 MB
  float* Opart         = (float*)(ws + ((size_t)53 << 20));          // 33.6 MB
  float* ML            = (float*)(ws + ((size_t)88 << 20));          // 1 MB
  unsigned short* bm16 = (unsigned short*)(ws + ((size_t)90 << 20)); // 128 MB

  k_cvt_bf16<<<dim3(512), dim3(256), 0, stream>>>(x, xb, 2048 * 1024 / 4);
  k_cvt_bf16<<<dim3(512), dim3(256), 0, stream>>>(w_qkv, wqb, 3072 * 1024 / 4);
  k_cvt_bf16<<<dim3(512), dim3(256), 0, stream>>>(w_out, wob, 1024 * 1024 / 4);
  k_rope_table<<<dim3(256), dim3(256), 0, stream>>>(cost, sint);
  k_mask<<<dim3(2048), dim3(256), 0, stream>>>(bias, mask, bm16, 2048 * 2048 * 16 / 8);
  k_gemm_bt<<<dim3(16, 24), dim3(256), 0, stream>>>(xb, wqb, b_qkv, qkv, 2048, 3072, 1024);
  k_rope_relayout<<<dim3(2048), dim3(256), 0, stream>>>(qkv, cost, sint, qhp, khp, vtp);
  k_attn<<<dim3(64, 4), dim3(1024), 0, stream>>>(bm16, qhp, khp, vtp, Opart, ML);
  k_combine<<<dim3(2048), dim3(256), 0, stream>>>(Opart, ML, af);
  k_gemm_bt<<<dim3(16, 8), dim3(256), 0, stream>>>(af, wob, b_out, out, 2048, 1024, 1024);
}